// Round 1
// baseline (195.948 us; speedup 1.0000x reference)
//
#include <hip/hip_runtime.h>

#define B_   16
#define C_   64
#define N_   2048
#define M_   (B_ * N_)     // 32768 points
#define K_   20
#define KS_  20
#define OC_  64
#define NWAVE2 8192        // waves in k_points

// ---------------------------------------------------------------------------
// K1: P[m][o] = sum_c W2[o][c]*flat[m][c];  Q[m][o] = sum_c (W1-W2)[o][c]*flat[m][c]
// flat[m][c] = feature[b][c][p], m = b*N+p.  pq layout: [m][128] = [P(64) | Q(64)]
// wave = 64 lanes, lane = output channel o. Weights live in 128 VGPRs; the
// feature vector is loaded one element per lane and broadcast via v_readlane.
// ---------------------------------------------------------------------------
__global__ __launch_bounds__(256) void k_project(
    const float* __restrict__ feat,     // [B][C][N]
    const float* __restrict__ conv_w,   // [OC][2C]
    float* __restrict__ pq)             // [M][128]
{
    const int lane = threadIdx.x & 63;
    const int wg   = blockIdx.x * 4 + (threadIdx.x >> 6);   // 0..2047
    // lane o preloads its weight rows: w2[c] = W2[o][c], wd[c] = (W1-W2)[o][c]
    float w2[64], wd[64];
    const float4* cw4 = (const float4*)conv_w;
    #pragma unroll
    for (int j = 0; j < 16; ++j) {
        float4 a = cw4[lane * 32 + j];        // W1 chunk
        float4 b = cw4[lane * 32 + 16 + j];   // W2 chunk
        w2[4*j+0] = b.x; w2[4*j+1] = b.y; w2[4*j+2] = b.z; w2[4*j+3] = b.w;
        wd[4*j+0] = a.x - b.x; wd[4*j+1] = a.y - b.y;
        wd[4*j+2] = a.z - b.z; wd[4*j+3] = a.w - b.w;
    }
    const int m0 = wg * 16;                   // 16 consecutive m per wave
    // software-pipelined feature loads (lane = channel c, stride-8KB gather;
    // consecutive p within the chunk -> full 64B-line reuse in L1)
    int b0 = m0 >> 11, p0 = m0 & 2047;
    float fv = feat[((size_t)(b0 * 64 + lane)) * 2048 + p0];
    for (int mi = 0; mi < 16; ++mi) {
        const int m = m0 + mi;
        float fnext = 0.f;
        if (mi < 15) {
            const int mn = m + 1;
            fnext = feat[((size_t)((mn >> 11) * 64 + lane)) * 2048 + (mn & 2047)];
        }
        float accP = 0.f, accQ = 0.f;
        #pragma unroll
        for (int c = 0; c < 64; ++c) {
            float fc = __int_as_float(
                __builtin_amdgcn_readlane(__float_as_int(fv), c));
            accP = fmaf(w2[c], fc, accP);
            accQ = fmaf(wd[c], fc, accQ);
        }
        pq[(size_t)m * 128 + lane]      = accP;   // coalesced 256B row
        pq[(size_t)m * 128 + 64 + lane] = accQ;
        fv = fnext;
    }
}

// ---------------------------------------------------------------------------
// K2: per point n (one wave per point, lane = o):
//   pk[k] = P[idx[n,k]][o] + Q[idx[n,0]][o]
//   acc[s] = b[o] + sum_k pk[k]*perm[n][k][s];  pre[n][o] = max_s acc[s]
// perm/idx rows are wave-uniform -> scalar loads; FMA = v_fmac(sgpr,vgpr).
// Also accumulates per-wave BN partial sums (sum, sumsq) per channel.
// ---------------------------------------------------------------------------
__global__ __launch_bounds__(256) void k_points(
    const float* __restrict__ pq,        // [M][128]
    const int*   __restrict__ nidx,      // [M][K]
    const float* __restrict__ perm,      // [M][K][KS]
    const float* __restrict__ conv_b,    // [OC]
    float* __restrict__ pre,             // [M][OC]
    float* __restrict__ partials)        // [NWAVE2][128] = [sum(64)|sumsq(64)]
{
    const int lane = threadIdx.x & 63;
    const int wg = __builtin_amdgcn_readfirstlane(
        (int)(blockIdx.x * 4 + (threadIdx.x >> 6)));       // 0..8191
    const float bias = conv_b[lane];
    float sum = 0.f, sumsq = 0.f;
    for (int it = 0; it < 4; ++it) {
        const int n = wg + NWAVE2 * it;
        const int*   __restrict__ ip = nidx + (size_t)n * K_;
        const float* __restrict__ pp = perm + (size_t)n * (K_ * KS_);
        float pk[20];
        #pragma unroll
        for (int k = 0; k < 20; ++k) {
            const int ik = ip[k];                          // uniform (s_load)
            pk[k] = pq[(size_t)ik * 128 + lane];           // coalesced 256B gather
        }
        const float q = pq[(size_t)ip[0] * 128 + 64 + lane];
        #pragma unroll
        for (int k = 0; k < 20; ++k) pk[k] += q;
        float acc[20];
        #pragma unroll
        for (int s = 0; s < 20; ++s) acc[s] = bias;
        #pragma unroll
        for (int k = 0; k < 20; ++k) {
            #pragma unroll
            for (int s = 0; s < 20; ++s)
                acc[s] = fmaf(pk[k], pp[k * 20 + s], acc[s]);  // perm uniform
        }
        float mv = acc[0];
        #pragma unroll
        for (int s = 1; s < 20; ++s) mv = fmaxf(mv, acc[s]);
        pre[(size_t)n * 64 + lane] = mv;
        sum += mv;
        sumsq = fmaf(mv, mv, sumsq);
    }
    partials[(size_t)wg * 128 + lane]      = sum;
    partials[(size_t)wg * 128 + 64 + lane] = sumsq;
}

// ---------------------------------------------------------------------------
// K2b: reduce partials per channel, fold BN+gamma/beta into scale/shift.
// stats[o] = gamma[o]*rsqrt(var+eps);  stats[64+o] = beta[o] - mean*scale
// fp64 accumulation: 64 blocks x 8192 adds, trivial cost, kills cancellation.
// ---------------------------------------------------------------------------
__global__ __launch_bounds__(256) void k_stats(
    const float* __restrict__ partials,  // [NWAVE2][128]
    const float* __restrict__ gamma,
    const float* __restrict__ beta,
    float* __restrict__ stats)           // [128]
{
    const int ch  = blockIdx.x;          // 0..63
    const int tid = threadIdx.x;
    double s = 0.0, s2 = 0.0;
    for (int w = tid; w < NWAVE2; w += 256) {
        s  += (double)partials[(size_t)w * 128 + ch];
        s2 += (double)partials[(size_t)w * 128 + 64 + ch];
    }
    __shared__ double sh_s[256];
    __shared__ double sh_q[256];
    sh_s[tid] = s; sh_q[tid] = s2;
    __syncthreads();
    for (int off = 128; off > 0; off >>= 1) {
        if (tid < off) { sh_s[tid] += sh_s[tid + off]; sh_q[tid] += sh_q[tid + off]; }
        __syncthreads();
    }
    if (tid == 0) {
        const double inv_n = 1.0 / (double)M_;
        double mean = sh_s[0] * inv_n;
        double var  = sh_q[0] * inv_n - mean * mean;
        double inv  = 1.0 / sqrt(var + 1e-5);
        double sc   = (double)gamma[ch] * inv;
        stats[ch]      = (float)sc;
        stats[64 + ch] = (float)((double)beta[ch] - mean * sc);
    }
}

// ---------------------------------------------------------------------------
// K3: y = pre*scale + shift, transposed [M][OC] -> [B][OC][N] via LDS 64x65.
// ---------------------------------------------------------------------------
__global__ __launch_bounds__(256) void k_apply(
    const float* __restrict__ pre,     // [M][OC]
    const float* __restrict__ stats,   // [128]
    float* __restrict__ out)           // [B][OC][N]
{
    __shared__ float tile[64 * 65];
    __shared__ float scl[64];
    __shared__ float shf[64];
    const int tid = threadIdx.x;
    if (tid < 64)       scl[tid]      = stats[tid];
    else if (tid < 128) shf[tid - 64] = stats[tid];
    __syncthreads();
    const int b  = blockIdx.x >> 5;
    const int pt = (blockIdx.x & 31) * 64;
    const int c  = tid & 63;
    const int r0 = tid >> 6;
    #pragma unroll
    for (int i = 0; i < 16; ++i) {
        const int r = i * 4 + r0;
        float v = pre[((size_t)(b * 2048 + pt + r)) * 64 + c];  // coalesced
        tile[c * 65 + r] = fmaf(v, scl[c], shf[c]);
    }
    __syncthreads();
    #pragma unroll
    for (int i = 0; i < 16; ++i) {
        const int o = i * 4 + r0;
        out[((size_t)(b * 64 + o)) * 2048 + pt + c] = tile[o * 65 + c]; // coalesced
    }
}

extern "C" void kernel_launch(void* const* d_in, const int* in_sizes, int n_in,
                              void* d_out, int out_size, void* d_ws, size_t ws_size,
                              hipStream_t stream) {
    const float* feat   = (const float*)d_in[0];
    const int*   nidx   = (const int*)  d_in[1];
    const float* perm   = (const float*)d_in[2];
    const float* conv_w = (const float*)d_in[3];
    const float* conv_b = (const float*)d_in[4];
    const float* gamma  = (const float*)d_in[5];
    const float* beta   = (const float*)d_in[6];
    float* out = (float*)d_out;

    char* ws = (char*)d_ws;
    float* pq       = (float*)ws;                                    // 16 MiB
    float* pre      = (float*)(ws + (size_t)M_ * 128 * 4);           //  8 MiB
    float* partials = (float*)(ws + (size_t)M_ * 128 * 4
                                  + (size_t)M_ * 64 * 4);            //  4 MiB
    float* stats    = (float*)(ws + (size_t)M_ * 128 * 4
                                  + (size_t)M_ * 64 * 4
                                  + (size_t)NWAVE2 * 128 * 4);       // 512 B

    hipLaunchKernelGGL(k_project, dim3(512),  dim3(256), 0, stream, feat, conv_w, pq);
    hipLaunchKernelGGL(k_points,  dim3(2048), dim3(256), 0, stream, pq, nidx, perm,
                       conv_b, pre, partials);
    hipLaunchKernelGGL(k_stats,   dim3(64),   dim3(256), 0, stream, partials, gamma,
                       beta, stats);
    hipLaunchKernelGGL(k_apply,   dim3(512),  dim3(256), 0, stream, pre, stats, out);
}

// Round 2
// 176.912 us; speedup vs baseline: 1.1076x; 1.1076x over previous
//
#include <hip/hip_runtime.h>

#define B_   16
#define C_   64
#define N_   2048
#define M_   (B_ * N_)     // 32768 points
#define K_   20
#define KS_  20
#define OC_  64
#define NWAVE2 8192        // waves in k_points

// async global->LDS, 16B per lane: LDS dest = uniform base + lane*16,
// global src = per-lane pointer.
__device__ __forceinline__ void load_lds16(const float* g, float* l) {
    __builtin_amdgcn_global_load_lds(
        (const __attribute__((address_space(1))) void*)g,
        (__attribute__((address_space(3))) void*)l, 16, 0, 0);
}

// ---------------------------------------------------------------------------
// K1: P[m][o] = sum_c W2[o][c]*flat[m][c];  Q[m][o] = sum_c (W1-W2)[o][c]*flat[m][c]
// wave = 64 lanes, lane = o. Weights in 128 VGPRs, feature broadcast via
// readlane. 4 accumulator chains to cover FMA latency.
// ---------------------------------------------------------------------------
__global__ __launch_bounds__(256) void k_project(
    const float* __restrict__ feat,     // [B][C][N]
    const float* __restrict__ conv_w,   // [OC][2C]
    float* __restrict__ pq)             // [M][128]
{
    const int lane = threadIdx.x & 63;
    const int wg   = blockIdx.x * 4 + (threadIdx.x >> 6);   // 0..2047
    float w2[64], wd[64];
    const float4* cw4 = (const float4*)conv_w;
    #pragma unroll
    for (int j = 0; j < 16; ++j) {
        float4 a = cw4[lane * 32 + j];        // W1 chunk
        float4 b = cw4[lane * 32 + 16 + j];   // W2 chunk
        w2[4*j+0] = b.x; w2[4*j+1] = b.y; w2[4*j+2] = b.z; w2[4*j+3] = b.w;
        wd[4*j+0] = a.x - b.x; wd[4*j+1] = a.y - b.y;
        wd[4*j+2] = a.z - b.z; wd[4*j+3] = a.w - b.w;
    }
    const int m0 = wg * 16;
    int b0 = m0 >> 11, p0 = m0 & 2047;
    float fv = feat[((size_t)(b0 * 64 + lane)) * 2048 + p0];
    for (int mi = 0; mi < 16; ++mi) {
        const int m = m0 + mi;
        float fnext = 0.f;
        if (mi < 15) {
            const int mn = m + 1;
            fnext = feat[((size_t)((mn >> 11) * 64 + lane)) * 2048 + (mn & 2047)];
        }
        float p0a = 0.f, p1a = 0.f, q0a = 0.f, q1a = 0.f;
        #pragma unroll
        for (int c = 0; c < 32; ++c) {
            float f0 = __int_as_float(
                __builtin_amdgcn_readlane(__float_as_int(fv), c));
            float f1 = __int_as_float(
                __builtin_amdgcn_readlane(__float_as_int(fv), c + 32));
            p0a = fmaf(w2[c], f0, p0a);
            p1a = fmaf(w2[c + 32], f1, p1a);
            q0a = fmaf(wd[c], f0, q0a);
            q1a = fmaf(wd[c + 32], f1, q1a);
        }
        pq[(size_t)m * 128 + lane]      = p0a + p1a;
        pq[(size_t)m * 128 + 64 + lane] = q0a + q1a;
        fv = fnext;
    }
}

// ---------------------------------------------------------------------------
// K2: per point n (wave = point, lane = o):
//   pk[k] = P[idx[n,k]][o] + Q[idx[n,0]][o]
//   acc[s] = b[o] + sum_k pk[k]*perm[n][k][s];  pre[n][o] = max_s acc[s]
// perm rows staged one point ahead via global_load_lds into a wave-private
// double-buffered LDS slice; consumed as uniform ds_read_b128 broadcasts
// (DS is in-order -> fine-grained waits; SMEM path eliminated).
// idx rows loaded as vector loads + readlane (vmcnt, no lgkm pollution).
// ---------------------------------------------------------------------------
__global__ __launch_bounds__(256) void k_points(
    const float* __restrict__ pq,        // [M][128]
    const int*   __restrict__ nidx,      // [M][K]
    const float* __restrict__ perm,      // [M][K][KS]
    const float* __restrict__ conv_b,    // [OC]
    float* __restrict__ pre,             // [M][OC]
    float* __restrict__ partials)        // [NWAVE2][128]
{
    __shared__ float plds[4 * 2 * 400];          // 12.8 KB: wave w at w*800
    const int tid  = threadIdx.x;
    const int lane = tid & 63;
    const int w    = __builtin_amdgcn_readfirstlane(tid >> 6);
    const int wg   = __builtin_amdgcn_readfirstlane((int)blockIdx.x * 4 + w);
    float* mybuf = &plds[w * 800];

    const float bias = conv_b[lane];
    float sum = 0.f, sumsq = 0.f;

    // prologue: stage point wg's perm into buf0; vector-load its idx row
    {
        const float* src = perm + (size_t)wg * 400;
        load_lds16(src + lane * 4, mybuf);
        if (lane < 36) load_lds16(src + 256 + lane * 4, mybuf + 256);
    }
    int iv = 0;
    if (lane < 20) iv = nidx[(size_t)wg * K_ + lane];

    #pragma unroll
    for (int it = 0; it < 4; ++it) {
        const int n = wg + NWAVE2 * it;
        float* cur = mybuf + (it & 1) * 400;
        // broadcast idx values to SGPRs (waits the idx vector load)
        int ik[20];
        #pragma unroll
        for (int k = 0; k < 20; ++k) ik[k] = __builtin_amdgcn_readlane(iv, k);
        // gathers: q first (so per-k waits stay fine-grained), then pk[k]
        float q = pq[(size_t)ik[0] * 128 + 64 + lane];
        float pk[20];
        #pragma unroll
        for (int k = 0; k < 20; ++k) pk[k] = pq[(size_t)ik[k] * 128 + lane];
        // prefetch next point: idx first, then perm staging (so a wait on idx
        // next iteration leaves the staging in flight)
        if (it < 3) {
            const int nn = n + NWAVE2;
            if (lane < 20) iv = nidx[(size_t)nn * K_ + lane];
            const float* src = perm + (size_t)nn * 400;
            float* nxt = mybuf + ((it + 1) & 1) * 400;
            load_lds16(src + lane * 4, nxt);
            if (lane < 36) load_lds16(src + 256 + lane * 4, nxt + 256);
        }
        // gathers + current staging retired; next idx+staging stay in flight.
        // simm16: vmcnt bits[3:0], expcnt bits[6:4]=7, lgkmcnt bits[11:8]=0xF
        if (it < 3) __builtin_amdgcn_s_waitcnt(0x0F74);   // vmcnt(4)
        else        __builtin_amdgcn_s_waitcnt(0x0F70);   // vmcnt(0)
        __asm__ volatile("" ::: "memory");                 // keep ds_reads below

        float acc[20];
        #pragma unroll
        for (int s = 0; s < 20; ++s) acc[s] = bias;
        #pragma unroll
        for (int k = 0; k < 20; ++k) {
            const float t = pk[k] + q;
            const float4* pr = (const float4*)(cur + k * 20);
            float4 a0 = pr[0], a1 = pr[1], a2 = pr[2], a3 = pr[3], a4 = pr[4];
            acc[ 0] = fmaf(t, a0.x, acc[ 0]); acc[ 1] = fmaf(t, a0.y, acc[ 1]);
            acc[ 2] = fmaf(t, a0.z, acc[ 2]); acc[ 3] = fmaf(t, a0.w, acc[ 3]);
            acc[ 4] = fmaf(t, a1.x, acc[ 4]); acc[ 5] = fmaf(t, a1.y, acc[ 5]);
            acc[ 6] = fmaf(t, a1.z, acc[ 6]); acc[ 7] = fmaf(t, a1.w, acc[ 7]);
            acc[ 8] = fmaf(t, a2.x, acc[ 8]); acc[ 9] = fmaf(t, a2.y, acc[ 9]);
            acc[10] = fmaf(t, a2.z, acc[10]); acc[11] = fmaf(t, a2.w, acc[11]);
            acc[12] = fmaf(t, a3.x, acc[12]); acc[13] = fmaf(t, a3.y, acc[13]);
            acc[14] = fmaf(t, a3.z, acc[14]); acc[15] = fmaf(t, a3.w, acc[15]);
            acc[16] = fmaf(t, a4.x, acc[16]); acc[17] = fmaf(t, a4.y, acc[17]);
            acc[18] = fmaf(t, a4.z, acc[18]); acc[19] = fmaf(t, a4.w, acc[19]);
        }
        float mv = acc[0];
        #pragma unroll
        for (int s = 1; s < 20; ++s) mv = fmaxf(mv, acc[s]);
        pre[(size_t)n * 64 + lane] = mv;
        sum += mv;
        sumsq = fmaf(mv, mv, sumsq);
    }
    partials[(size_t)wg * 128 + lane]      = sum;
    partials[(size_t)wg * 128 + 64 + lane] = sumsq;
}

// ---------------------------------------------------------------------------
// K2b: reduce partials per channel, fold BN+gamma/beta into scale/shift.
// ---------------------------------------------------------------------------
__global__ __launch_bounds__(256) void k_stats(
    const float* __restrict__ partials,  // [NWAVE2][128]
    const float* __restrict__ gamma,
    const float* __restrict__ beta,
    float* __restrict__ stats)           // [128]
{
    const int ch  = blockIdx.x;          // 0..63
    const int tid = threadIdx.x;
    double s = 0.0, s2 = 0.0;
    for (int w = tid; w < NWAVE2; w += 256) {
        s  += (double)partials[(size_t)w * 128 + ch];
        s2 += (double)partials[(size_t)w * 128 + 64 + ch];
    }
    __shared__ double sh_s[256];
    __shared__ double sh_q[256];
    sh_s[tid] = s; sh_q[tid] = s2;
    __syncthreads();
    for (int off = 128; off > 0; off >>= 1) {
        if (tid < off) { sh_s[tid] += sh_s[tid + off]; sh_q[tid] += sh_q[tid + off]; }
        __syncthreads();
    }
    if (tid == 0) {
        const double inv_n = 1.0 / (double)M_;
        double mean = sh_s[0] * inv_n;
        double var  = sh_q[0] * inv_n - mean * mean;
        double inv  = 1.0 / sqrt(var + 1e-5);
        double sc   = (double)gamma[ch] * inv;
        stats[ch]      = (float)sc;
        stats[64 + ch] = (float)((double)beta[ch] - mean * sc);
    }
}

// ---------------------------------------------------------------------------
// K3: y = pre*scale + shift, transposed [M][OC] -> [B][OC][N] via LDS 64x65.
// ---------------------------------------------------------------------------
__global__ __launch_bounds__(256) void k_apply(
    const float* __restrict__ pre,     // [M][OC]
    const float* __restrict__ stats,   // [128]
    float* __restrict__ out)           // [B][OC][N]
{
    __shared__ float tile[64 * 65];
    __shared__ float scl[64];
    __shared__ float shf[64];
    const int tid = threadIdx.x;
    if (tid < 64)       scl[tid]      = stats[tid];
    else if (tid < 128) shf[tid - 64] = stats[tid];
    __syncthreads();
    const int b  = blockIdx.x >> 5;
    const int pt = (blockIdx.x & 31) * 64;
    const int c  = tid & 63;
    const int r0 = tid >> 6;
    #pragma unroll
    for (int i = 0; i < 16; ++i) {
        const int r = i * 4 + r0;
        float v = pre[((size_t)(b * 2048 + pt + r)) * 64 + c];
        tile[c * 65 + r] = fmaf(v, scl[c], shf[c]);
    }
    __syncthreads();
    #pragma unroll
    for (int i = 0; i < 16; ++i) {
        const int o = i * 4 + r0;
        out[((size_t)(b * 64 + o)) * 2048 + pt + c] = tile[o * 65 + c];
    }
}

extern "C" void kernel_launch(void* const* d_in, const int* in_sizes, int n_in,
                              void* d_out, int out_size, void* d_ws, size_t ws_size,
                              hipStream_t stream) {
    const float* feat   = (const float*)d_in[0];
    const int*   nidx   = (const int*)  d_in[1];
    const float* perm   = (const float*)d_in[2];
    const float* conv_w = (const float*)d_in[3];
    const float* conv_b = (const float*)d_in[4];
    const float* gamma  = (const float*)d_in[5];
    const float* beta   = (const float*)d_in[6];
    float* out = (float*)d_out;

    char* ws = (char*)d_ws;
    float* pq       = (float*)ws;                                    // 16 MiB
    float* pre      = (float*)(ws + (size_t)M_ * 128 * 4);           //  8 MiB
    float* partials = (float*)(ws + (size_t)M_ * 128 * 4
                                  + (size_t)M_ * 64 * 4);            //  4 MiB
    float* stats    = (float*)(ws + (size_t)M_ * 128 * 4
                                  + (size_t)M_ * 64 * 4
                                  + (size_t)NWAVE2 * 128 * 4);       // 512 B

    hipLaunchKernelGGL(k_project, dim3(512),  dim3(256), 0, stream, feat, conv_w, pq);
    hipLaunchKernelGGL(k_points,  dim3(2048), dim3(256), 0, stream, pq, nidx, perm,
                       conv_b, pre, partials);
    hipLaunchKernelGGL(k_stats,   dim3(64),   dim3(256), 0, stream, partials, gamma,
                       beta, stats);
    hipLaunchKernelGGL(k_apply,   dim3(512),  dim3(256), 0, stream, pre, stats, out);
}